// Round 2
// baseline (4146.103 us; speedup 1.0000x reference)
//
#include <hip/hip_runtime.h>
#include <hip/hip_bf16.h>

#define HWDIM 96
#define TW 16
#define TH 4
#define NW 4   // waves per block (gate-channel split)

__device__ __forceinline__ float sigmoidf_fast(float x) {
    return 1.0f / (1.0f + __expf(-x));
}
__device__ __forceinline__ float tanhf_fast(float x) {
    return 2.0f / (1.0f + __expf(-2.0f * x)) - 1.0f;
}

// Fused ConvLSTM step: z = conv3x3(cat(x, h_prev)) + b ; gates ; c,h update.
// Block = (TW, TH, NW) = 256 threads. Each z-slice is one wave (16*4=64).
// Wave w computes hidden channels [w*CHID/NW, (w+1)*CHID/NW): all 4 gates each,
// so the c/h update is wave-local.
// Wt: (4*CHID, CIN_X+CHID, 3, 3), bias: (4*CHID)
// c_state: (B, CHID, 96, 96) in place; at h_zero (t==0) c_old := 0 (no read).
template<int CIN_X, int CHID>
__global__ __launch_bounds__(TW * TH * NW)
void convlstm_step(const float* __restrict__ x, long x_bstride,
                   const float* __restrict__ h_prev, long h_bstride, int h_zero,
                   const float* __restrict__ Wt, const float* __restrict__ bias,
                   float* __restrict__ c_state,
                   float* __restrict__ h_out, long hout_bstride) {
    constexpr int CTOT = CIN_X + CHID;
    constexpr int CPW = CHID / NW;       // hidden channels per wave
    constexpr int QS = CHID * CTOT * 9;  // weight stride between gate groups (i->f->o->g)
    constexpr int LH = TH + 2;
    constexpr int LW = TW + 2;

    __shared__ float tile[CTOT][LH][LW];

    const int tx = threadIdx.x;            // 0..TW-1
    const int ty = threadIdx.y;            // 0..TH-1
    const int tid = threadIdx.z * (TW * TH) + ty * TW + tx;
    const int x0 = blockIdx.x * TW;
    const int y0 = blockIdx.y * TH;
    const int b = blockIdx.z;
    // wave id, forced into an SGPR so weight/bias addressing stays scalar
    const int w = __builtin_amdgcn_readfirstlane(threadIdx.z);

    const float* xb = x + (long)b * x_bstride;
    const float* hb = h_prev + (long)b * h_bstride;

    // ---- stage input tile (with zero halo) into LDS, all 256 threads ----
    constexpr int TILE_N = CTOT * LH * LW;
    float* tflat = &tile[0][0][0];
    for (int i = tid; i < TILE_N; i += TW * TH * NW) {
        int c = i / (LH * LW);
        int rem = i % (LH * LW);
        int r = rem / LW;
        int cc = rem % LW;
        int gy = y0 + r - 1;
        int gx = x0 + cc - 1;
        float v = 0.0f;
        if ((unsigned)gy < (unsigned)HWDIM && (unsigned)gx < (unsigned)HWDIM) {
            if (c < CIN_X) {
                v = xb[(long)c * (HWDIM * HWDIM) + gy * HWDIM + gx];
            } else if (!h_zero) {
                v = hb[(long)(c - CIN_X) * (HWDIM * HWDIM) + gy * HWDIM + gx];
            }
        }
        tflat[i] = v;
    }
    __syncthreads();

    // ---- accumulate conv for this wave's CPW channels (4 gates each) ----
    float ai[CPW], af[CPW], ao[CPW], ag[CPW];
#pragma unroll
    for (int j = 0; j < CPW; ++j) {
        int gc = w * CPW + j;
        ai[j] = bias[gc];
        af[j] = bias[CHID + gc];
        ao[j] = bias[2 * CHID + gc];
        ag[j] = bias[3 * CHID + gc];
    }

    const float* Wv = Wt + (long)w * CPW * CTOT * 9;  // this wave's i-gate rows

#pragma unroll 2
    for (int ci = 0; ci < CTOT; ++ci) {
        float in9[9];
#pragma unroll
        for (int r = 0; r < 3; ++r)
#pragma unroll
            for (int cc = 0; cc < 3; ++cc)
                in9[r * 3 + cc] = tile[ci][ty + r][tx + cc];
#pragma unroll
        for (int j = 0; j < CPW; ++j) {
            const float* wi = Wv + (j * CTOT + ci) * 9;  // uniform -> s_load
#pragma unroll
            for (int k = 0; k < 9; ++k) {
                ai[j] = fmaf(in9[k], wi[k], ai[j]);
                af[j] = fmaf(in9[k], wi[k + QS], af[j]);
                ao[j] = fmaf(in9[k], wi[k + 2 * QS], ao[j]);
                ag[j] = fmaf(in9[k], wi[k + 3 * QS], ag[j]);
            }
        }
    }

    // ---- gates + state update (wave-local channels) ----
    const int sp = (y0 + ty) * HWDIM + (x0 + tx);
    float* cb = c_state + (long)b * (CHID * HWDIM * HWDIM);
    float* ho = h_out + (long)b * hout_bstride;
#pragma unroll
    for (int j = 0; j < CPW; ++j) {
        int hc = w * CPW + j;
        float si = sigmoidf_fast(ai[j]);
        float sf = sigmoidf_fast(af[j]);
        float so = sigmoidf_fast(ao[j]);
        float tg = tanhf_fast(ag[j]);
        long ofs = (long)hc * (HWDIM * HWDIM) + sp;
        float c_old = h_zero ? 0.0f : cb[ofs];
        float cn = sf * c_old + si * tg;
        float hn = so * tanhf_fast(cn);
        cb[ofs] = cn;
        ho[ofs] = hn;
    }
}

extern "C" void kernel_launch(void* const* d_in, const int* in_sizes, int n_in,
                              void* d_out_v, int out_size, void* d_ws, size_t ws_size,
                              hipStream_t stream) {
    const float* x  = (const float*)d_in[0];
    const float* W1 = (const float*)d_in[1];
    const float* b1 = (const float*)d_in[2];
    const float* W2 = (const float*)d_in[3];
    const float* b2 = (const float*)d_in[4];
    const float* W3 = (const float*)d_in[5];
    const float* b3 = (const float*)d_in[6];
    float* out = (float*)d_out_v;
    float* ws = (float*)d_ws;

    const int HW2 = HWDIM * HWDIM;  // 9216
    const int B = 8, T = 24;

    // workspace layout (floats)
    float* c1  = ws;                          // 8*16*9216
    float* c2  = c1 + (long)B * 16 * HW2;     // 8*8*9216
    float* c3  = c2 + (long)B * 8 * HW2;      // 8*16*9216
    float* o1a = c3 + (long)B * 16 * HW2;
    float* o1b = o1a + (long)B * 16 * HW2;
    float* o2a = o1b + (long)B * 16 * HW2;
    float* o2b = o2a + (long)B * 8 * HW2;
    float* out1buf[2] = {o1a, o1b};
    float* out2buf[2] = {o2a, o2b};

    dim3 grid(HWDIM / TW, HWDIM / TH, B);
    dim3 blk(TW, TH, NW);

    for (int t = 0; t < T; ++t) {
        int p = t & 1, q = p ^ 1;
        // Layer 1: x_t from input seq, h from out1[prev]
        convlstm_step<16, 16><<<grid, blk, 0, stream>>>(
            x + (long)t * 16 * HW2, (long)T * 16 * HW2,
            out1buf[q], (long)16 * HW2, t == 0,
            W1, b1, c1,
            out1buf[p], (long)16 * HW2);
        // Layer 2: x = out1[t], h from out2[prev]
        convlstm_step<16, 8><<<grid, blk, 0, stream>>>(
            out1buf[p], (long)16 * HW2,
            out2buf[q], (long)8 * HW2, t == 0,
            W2, b2, c2,
            out2buf[p], (long)8 * HW2);
        // Layer 3: x = out2[t], h from d_out at t-1, h_out -> d_out at t
        convlstm_step<8, 16><<<grid, blk, 0, stream>>>(
            out2buf[p], (long)8 * HW2,
            (t == 0) ? out : out + (long)(t - 1) * 16 * HW2, (long)T * 16 * HW2, t == 0,
            W3, b3, c3,
            out + (long)t * 16 * HW2, (long)T * 16 * HW2);
    }

    // append final bottleneck states: h2 = out2 written at t=23 (odd -> buf[1]), c2
    long n3 = (long)B * T * 16 * HW2;            // 28,311,552
    long nh2 = (long)B * 8 * HW2;                // 589,824
    hipMemcpyAsync(out + n3, out2buf[1], nh2 * sizeof(float),
                   hipMemcpyDeviceToDevice, stream);
    hipMemcpyAsync(out + n3 + nh2, c2, nh2 * sizeof(float),
                   hipMemcpyDeviceToDevice, stream);
}

// Round 3
// 3447.342 us; speedup vs baseline: 1.2027x; 1.2027x over previous
//
#include <hip/hip_runtime.h>
#include <hip/hip_bf16.h>

#define HWDIM 96
#define TW 16
#define TH 4
#define NW 8      // waves per block (gate-channel split); 512 threads
#define LWPAD 24  // padded LDS row stride (floats): rows map 2x per bank = free

__device__ __forceinline__ float sigmoidf_fast(float x) {
    return 1.0f / (1.0f + __expf(-x));
}
__device__ __forceinline__ float tanhf_fast(float x) {
    return 2.0f / (1.0f + __expf(-2.0f * x)) - 1.0f;
}

// Fused ConvLSTM step: z = conv3x3(cat(x, h_prev)) + b ; gates ; c,h update.
// Block = (TW, TH, NW) = 512 threads; each z-slice is one wave (16*4=64).
// Wave w computes hidden channels [w*CHID/NW, (w+1)*CHID/NW): all 4 gates each,
// so the c/h update is wave-local. 4 blocks/CU resident -> 32 waves/CU.
// Wt: (4*CHID, CIN_X+CHID, 3, 3), bias: (4*CHID)
// c_state: (B, CHID, 96, 96) in place; at h_zero (t==0) c_old := 0 (no read).
template<int CIN_X, int CHID>
__global__ __launch_bounds__(TW * TH * NW)
void convlstm_step(const float* __restrict__ x, long x_bstride,
                   const float* __restrict__ h_prev, long h_bstride, int h_zero,
                   const float* __restrict__ Wt, const float* __restrict__ bias,
                   float* __restrict__ c_state,
                   float* __restrict__ h_out, long hout_bstride) {
    constexpr int CTOT = CIN_X + CHID;
    constexpr int CPW = CHID / NW;       // hidden channels per wave (>=1)
    constexpr int QS = CHID * CTOT * 9;  // weight stride between gate groups
    constexpr int LH = TH + 2;
    constexpr int LW = TW + 2;           // logical tile width (halo)

    __shared__ float tile[CTOT][LH][LWPAD];

    const int tx = threadIdx.x;            // 0..TW-1
    const int ty = threadIdx.y;            // 0..TH-1
    const int tid = threadIdx.z * (TW * TH) + ty * TW + tx;
    const int x0 = blockIdx.x * TW;
    const int y0 = blockIdx.y * TH;
    const int b = blockIdx.z;
    // wave id, forced into an SGPR so weight/bias addressing stays scalar
    const int w = __builtin_amdgcn_readfirstlane(threadIdx.z);

    const float* xb = x + (long)b * x_bstride;
    const float* hb = h_prev + (long)b * h_bstride;

    // ---- stage input tile (with zero halo) into LDS, all 512 threads ----
    constexpr int TILE_N = CTOT * LH * LW;
    for (int i = tid; i < TILE_N; i += TW * TH * NW) {
        int c = i / (LH * LW);
        int rem = i % (LH * LW);
        int r = rem / LW;
        int cc = rem % LW;
        int gy = y0 + r - 1;
        int gx = x0 + cc - 1;
        float v = 0.0f;
        if ((unsigned)gy < (unsigned)HWDIM && (unsigned)gx < (unsigned)HWDIM) {
            if (c < CIN_X) {
                v = xb[(long)c * (HWDIM * HWDIM) + gy * HWDIM + gx];
            } else if (!h_zero) {
                v = hb[(long)(c - CIN_X) * (HWDIM * HWDIM) + gy * HWDIM + gx];
            }
        }
        tile[c][r][cc] = v;
    }
    __syncthreads();

    // ---- accumulate conv for this wave's CPW channels (4 gates each) ----
    float ai[CPW], af[CPW], ao[CPW], ag[CPW];
#pragma unroll
    for (int j = 0; j < CPW; ++j) {
        int gc = w * CPW + j;
        ai[j] = bias[gc];
        af[j] = bias[CHID + gc];
        ao[j] = bias[2 * CHID + gc];
        ag[j] = bias[3 * CHID + gc];
    }

    const float* Wv = Wt + (long)w * CPW * CTOT * 9;  // this wave's i-gate rows

#pragma unroll 2
    for (int ci = 0; ci < CTOT; ++ci) {
        float in9[9];
#pragma unroll
        for (int r = 0; r < 3; ++r)
#pragma unroll
            for (int cc = 0; cc < 3; ++cc)
                in9[r * 3 + cc] = tile[ci][ty + r][tx + cc];
#pragma unroll
        for (int j = 0; j < CPW; ++j) {
            const float* wi = Wv + (j * CTOT + ci) * 9;  // uniform -> s_load
#pragma unroll
            for (int k = 0; k < 9; ++k) {
                ai[j] = fmaf(in9[k], wi[k], ai[j]);
                af[j] = fmaf(in9[k], wi[k + QS], af[j]);
                ao[j] = fmaf(in9[k], wi[k + 2 * QS], ao[j]);
                ag[j] = fmaf(in9[k], wi[k + 3 * QS], ag[j]);
            }
        }
    }

    // ---- gates + state update (wave-local channels) ----
    const int sp = (y0 + ty) * HWDIM + (x0 + tx);
    float* cb = c_state + (long)b * (CHID * HWDIM * HWDIM);
    float* ho = h_out + (long)b * hout_bstride;
#pragma unroll
    for (int j = 0; j < CPW; ++j) {
        int hc = w * CPW + j;
        float si = sigmoidf_fast(ai[j]);
        float sf = sigmoidf_fast(af[j]);
        float so = sigmoidf_fast(ao[j]);
        float tg = tanhf_fast(ag[j]);
        long ofs = (long)hc * (HWDIM * HWDIM) + sp;
        float c_old = h_zero ? 0.0f : cb[ofs];
        float cn = sf * c_old + si * tg;
        float hn = so * tanhf_fast(cn);
        cb[ofs] = cn;
        ho[ofs] = hn;
    }
}

extern "C" void kernel_launch(void* const* d_in, const int* in_sizes, int n_in,
                              void* d_out_v, int out_size, void* d_ws, size_t ws_size,
                              hipStream_t stream) {
    const float* x  = (const float*)d_in[0];
    const float* W1 = (const float*)d_in[1];
    const float* b1 = (const float*)d_in[2];
    const float* W2 = (const float*)d_in[3];
    const float* b2 = (const float*)d_in[4];
    const float* W3 = (const float*)d_in[5];
    const float* b3 = (const float*)d_in[6];
    float* out = (float*)d_out_v;
    float* ws = (float*)d_ws;

    const int HW2 = HWDIM * HWDIM;  // 9216
    const int B = 8, T = 24;

    // workspace layout (floats)
    float* c1  = ws;                          // 8*16*9216
    float* c2  = c1 + (long)B * 16 * HW2;     // 8*8*9216
    float* c3  = c2 + (long)B * 8 * HW2;      // 8*16*9216
    float* o1a = c3 + (long)B * 16 * HW2;
    float* o1b = o1a + (long)B * 16 * HW2;
    float* o2a = o1b + (long)B * 16 * HW2;
    float* o2b = o2a + (long)B * 8 * HW2;
    float* out1buf[2] = {o1a, o1b};
    float* out2buf[2] = {o2a, o2b};

    dim3 grid(HWDIM / TW, HWDIM / TH, B);
    dim3 blk(TW, TH, NW);

    for (int t = 0; t < T; ++t) {
        int p = t & 1, q = p ^ 1;
        // Layer 1: x_t from input seq, h from out1[prev]
        convlstm_step<16, 16><<<grid, blk, 0, stream>>>(
            x + (long)t * 16 * HW2, (long)T * 16 * HW2,
            out1buf[q], (long)16 * HW2, t == 0,
            W1, b1, c1,
            out1buf[p], (long)16 * HW2);
        // Layer 2: x = out1[t], h from out2[prev]
        convlstm_step<16, 8><<<grid, blk, 0, stream>>>(
            out1buf[p], (long)16 * HW2,
            out2buf[q], (long)8 * HW2, t == 0,
            W2, b2, c2,
            out2buf[p], (long)8 * HW2);
        // Layer 3: x = out2[t], h from d_out at t-1, h_out -> d_out at t
        convlstm_step<8, 16><<<grid, blk, 0, stream>>>(
            out2buf[p], (long)8 * HW2,
            (t == 0) ? out : out + (long)(t - 1) * 16 * HW2, (long)T * 16 * HW2, t == 0,
            W3, b3, c3,
            out + (long)t * 16 * HW2, (long)T * 16 * HW2);
    }

    // append final bottleneck states: h2 = out2 written at t=23 (odd -> buf[1]), c2
    long n3 = (long)B * T * 16 * HW2;            // 28,311,552
    long nh2 = (long)B * 8 * HW2;                // 589,824
    hipMemcpyAsync(out + n3, out2buf[1], nh2 * sizeof(float),
                   hipMemcpyDeviceToDevice, stream);
    hipMemcpyAsync(out + n3 + nh2, c2, nh2 * sizeof(float),
                   hipMemcpyDeviceToDevice, stream);
}